// Round 8
// baseline (268.589 us; speedup 1.0000x reference)
//
#include <hip/hip_runtime.h>
#include <math.h>

// DTW 2048x2048, squared-diff cost, out = sqrt(DTW[2047][2047]).
//
// TWO-CU pipeline: 2 blocks x 4 waves (1 wave/SIMD on two CUs), 8 strips
// of 256 rows; strip g = 4*blockIdx + w; lane l owns strip rows 4l..4l+3.
// Engine = R7's proven 2-col/step core (cols jA=tau0+2s-2l, jB=jA+1).
//
// WHY (rounds 0-7 evidence): single-wave issue cadence ~5.3cy/VALU is the
// binding limit (R7: 1376 steps x 44 ops = 235cy/step; R0/R5: 31 ops =
// 140-144cy; dependency structure irrelevant). 2 waves/SIMD convoy at
// 3.45cy/op (R3) - net loss with ramp. Remaining big lever: MORE CUs at
// 1 wave/SIMD. R6 tried this and the container died: it streamed a ~9KB
// ring into d_ws with NO size check -> OOB store. This round guards
// ws_size (fallback = R7 kernel verbatim) and keeps the protocol.
// Model: 25 ops/step x 5.3 = 133cy/step; GTOT 3648 -> 1824 steps = 101us.
//
// Cross-CU edge (strip 3 -> 4) via global ring in d_ws + flag:
//   producer (b0,w3): per step one relaxed-agent atomic 8B store of
//     (n3A,n3B); per block: __threadfence() then lane0 release-store
//     flag = tau0+64. Final flag = 2176.
//   consumer (b1,w0): col c is final once producer's lane63 wrote it
//     (c <= tau0_p-63), i.e. consuming block tau0 needs flag >= tau0+192.
//     EXTRA=128 skew for b1 => in steady state the NEXT block's target
//     (tau0+64+192) trails the published flag by 64 cols -> prefetch the
//     next block's 64 ring values right after spin, consume them a block
//     later (HBM latency hidden under 32 steps of compute).
//   junk safety: cols 2050..2175 are never lane63-final; they are beyond
//     col 2047 and DP deps flow rightward only -> can't reach the output.
//     Negative/NaN poison sorts LARGE under unsigned-bitcast min.
//   flag zeroed per launch by hipMemsetAsync (graph-capture legal).
//
// Intra-block handoffs: LDS ring rows w->w+1, DSKEW=192 + barrier per
// 64-col block (R7's proof: producer's completed cols >= tau0+65 at the
// consumer's barrier). b1/w3 (matrix bottom) writes nothing.
//
// Per block, per wave: 1 ring read (LDS or global), y window as f32x2
// loads; per step: 2 readlane + 2 dpp_shr1 conveyor, 4 v_pk_add_f32,
// 8 min3 (unsigned-bitcast, fuses to v_min3_u32), 8 fma, 1 8B store.
//
// Output: strip 7 = b1/w3, lane 63, row 3 (global 2047), tau0==2112,
// s==30 -> jB = 2112+61-126 = 2047.

#define NLEN   2048
#define NWL    4
#define CSTEP  64
#define SPB    (CSTEP / 2)
#define DSKEW  192
#define EXTRA  128                     // extra skew for block 1 (flag slack)
#define PAD    128
#define RROW   (PAD + 2176)            // ring cols -128..2175 -> 2304 floats
#define YPAD   128
#define TAUMAX 2112
#define GTOT   (TAUMAX + 7 * DSKEW + EXTRA + CSTEP)   // 3648
#define FLAG_FINAL (TAUMAX + CSTEP)    // 2176
#define INFV   1e30f

typedef float f32x2 __attribute__((ext_vector_type(2)));
typedef unsigned long long u64;

__device__ __forceinline__ float dpp_shr1(float v, float inj) {
    int r = __builtin_amdgcn_update_dpp(
        __builtin_bit_cast(int, inj), __builtin_bit_cast(int, v),
        0x138 /*wave_shr:1*/, 0xF, 0xF, false /*lane0 keeps old=inj*/);
    return __builtin_bit_cast(float, r);
}
__device__ __forceinline__ float rdlane(float v, int l) {
    return __builtin_bit_cast(float,
        __builtin_amdgcn_readlane(__builtin_bit_cast(int, v), l));
}
// 3-input min on non-negative floats via unsigned bit-pattern compare;
// umin+umin fuses to a single v_min3_u32. NaN/inf/negative sort LARGE.
__device__ __forceinline__ float min3f(float a, float b, float c) {
    unsigned ia = __builtin_bit_cast(unsigned, a);
    unsigned ib = __builtin_bit_cast(unsigned, b);
    unsigned ic = __builtin_bit_cast(unsigned, c);
    unsigned m  = __builtin_elementwise_min(
                      __builtin_elementwise_min(ia, ib), ic);
    return __builtin_bit_cast(float, m);
}
__device__ __forceinline__ void spinflag(int* flag, int target) {
    while (__hip_atomic_load(flag, __ATOMIC_ACQUIRE,
                             __HIP_MEMORY_SCOPE_AGENT) < target)
        __builtin_amdgcn_s_sleep(2);
}
__device__ __forceinline__ float gload(const float* p) {
    unsigned u = __hip_atomic_load((const unsigned*)p, __ATOMIC_RELAXED,
                                   __HIP_MEMORY_SCOPE_AGENT);
    return __builtin_bit_cast(float, u);
}

// ---------------- 2-block (2-CU) kernel ----------------
__global__ __launch_bounds__(256, 1) void dtw_kernel(const float* __restrict__ X,
                                                     const float* __restrict__ Y,
                                                     float* __restrict__ out,
                                                     float* __restrict__ ws) {
    int*   flag = (int*)ws;
    float* grow = ws + 16 + PAD;       // global ring base (col 0)

    __shared__ __align__(16) float yB[YPAD + NLEN + YPAD];
    __shared__ float ring[(NWL + 1) * RROW];
    float* yS = yB + YPAD;

    const int tid  = threadIdx.x;
    const int w    = tid >> 6;
    const int lane = tid & 63;
    const int b    = blockIdx.x;
    const int skew = (4 * b + w) * DSKEW + (b ? EXTRA : 0);
    // roles: 0 = LDS->LDS, 1 = producer (b0,w3), 2 = consumer (b1,w0),
    //        3 = bottom strip (b1,w3): no writes, owns the output.
    const int role = (b == 0) ? (w == 3 ? 1 : 0) : (w == 0 ? 2 : (w == 3 ? 3 : 0));

    {   // Y into LDS middle, INFV pads on both sides
        const float4* Y4 = (const float4*)Y;
        float4* y4 = (float4*)(yB + YPAD);
        y4[tid]       = Y4[tid];
        y4[tid + 256] = Y4[tid + 256];
        if (tid < YPAD) {
            yB[tid]               = INFV;
            yB[YPAD + NLEN + tid] = INFV;
        }
    }
    for (int k = tid; k < (NWL + 1) * RROW; k += 256) ring[k] = INFV;
    __syncthreads();

    f32x2 xx0, xx1, xx2, xx3;
    {   // strip rows: 256*(4b+w) + 4*lane
        const float4 xa = *(const float4*)&X[b * 1024 + w * 256 + lane * 4];
        xx0 = (f32x2){xa.x, xa.x}; xx1 = (f32x2){xa.y, xa.y};
        xx2 = (f32x2){xa.z, xa.z}; xx3 = (f32x2){xa.w, xa.w};
    }

    float pB0 = INFV, pB1 = INFV, pB2 = INFV, pB3 = INFV;
    float a3p = INFV;
    float uBp = (b == 0 && tid == 0) ? 0.0f : INFV;  // DTW[-1][-1]=0 seed
    float gcur = INFV, gnext = INFV;                 // consumer prefetch regs

    const float* ringR = ring + w * RROW + PAD;
    float*       ringW = ring + (w + 1) * RROW + PAD;

    for (int gb = 0; gb < GTOT; gb += CSTEP) {
        const int tau0 = gb - skew;

        if (tau0 >= 0 && tau0 <= TAUMAX) {
            float rblk;
            if (role == 2) {
                if (tau0 == 0) {                       // prologue: current block
                    spinflag(flag, 192);
                    gcur = gload(grow + lane);
                }
                const int nt = tau0 + CSTEP;           // prefetch next block
                if (nt <= TAUMAX) {
                    int tgt = nt + 192;
                    if (tgt > FLAG_FINAL) tgt = FLAG_FINAL;
                    spinflag(flag, tgt);
                    gnext = gload(grow + nt + lane);
                }
                rblk = gcur;
            } else {
                rblk = ringR[tau0 + lane];             // 1 coalesced ds_read
            }

            f32x2 y2[SPB];
            {
                const f32x2* yp = (const f32x2*)(yS + (tau0 - 2 * lane));
                #pragma unroll
                for (int k = 0; k < SPB; ++k) y2[k] = yp[k];
            }
            float* wp = ringW + (tau0 - 2 * lane);
            u64*   gw = (u64*)(grow + (tau0 - 2 * lane));
            const bool isout = (role == 3) & (lane == 63) & (tau0 == TAUMAX);

            #pragma unroll
            for (int s = 0; s < SPB; ++s) {
                const float riA = rdlane(rblk, 2 * s);
                const float riB = rdlane(rblk, 2 * s + 1);
                const float uA  = dpp_shr1(a3p, riA);
                const float uB  = dpp_shr1(pB3, riB);
                const f32x2 yv = y2[s];
                f32x2 d0 = xx0 - yv;
                float n0A = fmaf(d0.x, d0.x, min3f(pB0, uA,  uBp));
                float n0B = fmaf(d0.y, d0.y, min3f(n0A, uB,  uA));
                f32x2 d1 = xx1 - yv;
                float n1A = fmaf(d1.x, d1.x, min3f(pB1, n0A, pB0));
                float n1B = fmaf(d1.y, d1.y, min3f(n1A, n0B, n0A));
                f32x2 d2 = xx2 - yv;
                float n2A = fmaf(d2.x, d2.x, min3f(pB2, n1A, pB1));
                float n2B = fmaf(d2.y, d2.y, min3f(n2A, n1B, n1A));
                f32x2 d3 = xx3 - yv;
                float n3A = fmaf(d3.x, d3.x, min3f(pB3, n2A, pB2));
                float n3B = fmaf(d3.y, d3.y, min3f(n3A, n2B, n2A));
                f32x2 wv; wv.x = n3A; wv.y = n3B;
                if (role == 1) {
                    __hip_atomic_store(gw + s, __builtin_bit_cast(u64, wv),
                                       __ATOMIC_RELAXED, __HIP_MEMORY_SCOPE_AGENT);
                } else if (role != 3) {
                    *(f32x2*)(wp + 2 * s) = wv;        // ds_write_b64
                }
                uBp = uB; a3p = n3A;
                pB0 = n0B; pB1 = n1B; pB2 = n2B; pB3 = n3B;
                if (s == 30 && isout) out[0] = sqrtf(n3B);  // col 2047
            }

            if (role == 1) {
                __threadfence();
                if (lane == 0)
                    __hip_atomic_store(flag, tau0 + CSTEP, __ATOMIC_RELEASE,
                                       __HIP_MEMORY_SCOPE_AGENT);
            }
            if (role == 2) gcur = gnext;
        }
        __syncthreads();
    }
}

// ---------------- fallback: R7 single-block kernel (proven 134.5us) ----------------
#define FNW    4
#define FDSKEW 192
#define FGTOT  (TAUMAX + (FNW - 1) * FDSKEW + CSTEP)   // 2752

__global__ __launch_bounds__(256, 1) void dtw_kernel_fb(const float* __restrict__ X,
                                                        const float* __restrict__ Y,
                                                        float* __restrict__ out) {
    __shared__ __align__(16) float yB[YPAD + NLEN + YPAD];
    __shared__ float ring[(FNW + 1) * RROW];
    float* yS = yB + YPAD;

    const int tid  = threadIdx.x;
    const int w    = tid >> 6;
    const int lane = tid & 63;

    {
        const float4* Y4 = (const float4*)Y;
        float4* y4 = (float4*)(yB + YPAD);
        y4[tid]       = Y4[tid];
        y4[tid + 256] = Y4[tid + 256];
        if (tid < YPAD) {
            yB[tid]               = INFV;
            yB[YPAD + NLEN + tid] = INFV;
        }
    }
    for (int k = tid; k < (FNW + 1) * RROW; k += 256) ring[k] = INFV;
    __syncthreads();

    f32x2 xx0, xx1, xx2, xx3, xx4, xx5, xx6, xx7;
    {
        const float4 xa = *(const float4*)&X[tid * 8];
        const float4 xb = *(const float4*)&X[tid * 8 + 4];
        xx0 = (f32x2){xa.x, xa.x}; xx1 = (f32x2){xa.y, xa.y};
        xx2 = (f32x2){xa.z, xa.z}; xx3 = (f32x2){xa.w, xa.w};
        xx4 = (f32x2){xb.x, xb.x}; xx5 = (f32x2){xb.y, xb.y};
        xx6 = (f32x2){xb.z, xb.z}; xx7 = (f32x2){xb.w, xb.w};
    }

    float pB0 = INFV, pB1 = INFV, pB2 = INFV, pB3 = INFV;
    float pB4 = INFV, pB5 = INFV, pB6 = INFV, pB7 = INFV;
    float a7p = INFV;
    float uBp = (tid == 0) ? 0.0f : INFV;

    const float* ringR = ring + w * RROW + PAD;
    float*       ringW = ring + (w + 1) * RROW + PAD;

    for (int gb = 0; gb < FGTOT; gb += CSTEP) {
        const int tau0 = gb - w * FDSKEW;

        if (tau0 >= 0 && tau0 <= TAUMAX) {
            const float rblk = ringR[tau0 + lane];
            f32x2 y2[SPB];
            {
                const f32x2* yp = (const f32x2*)(yS + (tau0 - 2 * lane));
                #pragma unroll
                for (int k = 0; k < SPB; ++k) y2[k] = yp[k];
            }
            float* wp = ringW + (tau0 - 2 * lane);
            const bool isout = (tau0 == TAUMAX) & (w == FNW - 1) & (lane == 63);

            #pragma unroll
            for (int s = 0; s < SPB; ++s) {
                const float riA = rdlane(rblk, 2 * s);
                const float riB = rdlane(rblk, 2 * s + 1);
                const float uA  = dpp_shr1(a7p, riA);
                const float uB  = dpp_shr1(pB7, riB);
                const f32x2 yv = y2[s];
                f32x2 d0 = xx0 - yv;
                float n0A = fmaf(d0.x, d0.x, min3f(pB0, uA,  uBp));
                float n0B = fmaf(d0.y, d0.y, min3f(n0A, uB,  uA));
                f32x2 d1 = xx1 - yv;
                float n1A = fmaf(d1.x, d1.x, min3f(pB1, n0A, pB0));
                float n1B = fmaf(d1.y, d1.y, min3f(n1A, n0B, n0A));
                f32x2 d2 = xx2 - yv;
                float n2A = fmaf(d2.x, d2.x, min3f(pB2, n1A, pB1));
                float n2B = fmaf(d2.y, d2.y, min3f(n2A, n1B, n1A));
                f32x2 d3 = xx3 - yv;
                float n3A = fmaf(d3.x, d3.x, min3f(pB3, n2A, pB2));
                float n3B = fmaf(d3.y, d3.y, min3f(n3A, n2B, n2A));
                f32x2 d4 = xx4 - yv;
                float n4A = fmaf(d4.x, d4.x, min3f(pB4, n3A, pB3));
                float n4B = fmaf(d4.y, d4.y, min3f(n4A, n3B, n3A));
                f32x2 d5 = xx5 - yv;
                float n5A = fmaf(d5.x, d5.x, min3f(pB5, n4A, pB4));
                float n5B = fmaf(d5.y, d5.y, min3f(n5A, n4B, n4A));
                f32x2 d6 = xx6 - yv;
                float n6A = fmaf(d6.x, d6.x, min3f(pB6, n5A, pB5));
                float n6B = fmaf(d6.y, d6.y, min3f(n6A, n5B, n5A));
                f32x2 d7 = xx7 - yv;
                float n7A = fmaf(d7.x, d7.x, min3f(pB7, n6A, pB6));
                float n7B = fmaf(d7.y, d7.y, min3f(n7A, n6B, n6A));
                f32x2 wv; wv.x = n7A; wv.y = n7B;
                *(f32x2*)(wp + 2 * s) = wv;
                uBp = uB; a7p = n7A;
                pB0 = n0B; pB1 = n1B; pB2 = n2B; pB3 = n3B;
                pB4 = n4B; pB5 = n5B; pB6 = n6B; pB7 = n7B;
                if (s == 30 && isout) out[0] = sqrtf(n7B);
            }
        }
        __syncthreads();
    }
}

extern "C" void kernel_launch(void* const* d_in, const int* in_sizes, int n_in,
                              void* d_out, int out_size, void* d_ws, size_t ws_size,
                              hipStream_t stream) {
    const float* x = (const float*)d_in[0];
    const float* y = (const float*)d_in[1];
    (void)in_sizes; (void)n_in; (void)out_size;
    if (d_ws != nullptr && ws_size >= 16384) {
        hipMemsetAsync(d_ws, 0, 4, stream);          // zero the flag
        dtw_kernel<<<2, 256, 0, stream>>>(x, y, (float*)d_out, (float*)d_ws);
    } else {
        dtw_kernel_fb<<<1, 256, 0, stream>>>(x, y, (float*)d_out);
    }
}

// Round 9
// 198.099 us; speedup vs baseline: 1.3558x; 1.3558x over previous
//
#include <hip/hip_runtime.h>
#include <math.h>

// DTW 2048x2048, squared-diff cost, out = sqrt(DTW[2047][2047]).
//
// NW=8 waves (512 thr, 2 waves/SIMD), R=4 rows/lane, C=2 cols/step.
// Strip w = rows 256w..+255; lane l owns strip rows 4l..4l+3; at step s
// of block tau0 it computes cols jA = tau0+2s-2l, jB = jA+1.
//
// WHY (rounds 0-8 evidence): lone-wave issue cadence ~4.5-5.3 cy/VALU is
// the binding limit (R0/R5/R7; dependency structure irrelevant). R3
// measured 2 waves/SIMD at 3.45 cy/op AGGREGATE (1.5x per-SIMD) but lost
// on its fat C=1 engine + ramp. R8's 2-CU handoff throttled on uncached
// per-step all-lane stores (WRITE_SIZE 570KB, producer ~450cy/step).
// This round: the lean C=2 engine (R7: 25 ops/step at R=4) x 8 waves,
// CSTEP 64->32 so DSKEW drops 192->160 (ramp 1344->1120 cols).
// Model: 1648 steps x (50 ops/SIMD x 3.45/2) ~ 172cy -> ~118us vs 134.5.
//
// Per block (32 cols), per wave: 1 coalesced ds_read (ring cols
// tau0..tau0+63, readlane-indexed 0..31), 16 f32x2 y-window loads
// (cols tau0-2l..+31, INFV-padded yB keeps them in-bounds); per step:
// 2 readlane + 2 dpp_shr1 (u conveyor: lane l gets lane l-1's row-3
// pair; lane 0 injects ring = row above strip), 4 v_pk_add_f32 (subs),
// 8 min3 (unsigned-bitcast, fuses v_min3_u32), 8 fma, 1 ds_write_b64.
//
// Ring proof (DSKEW=160, CSTEP=32): consumer readlane-uses ring cols
// <= tau0+31. Producer wave w-1 at the shared barrier completed blocks
// through tau0+DSKEW-CSTEP = tau0+128; its lane63 (lag 126) wrote cols
// <= tau0+128+31-126 = tau0+33 >= tau0+31. Lane 63 writes each col last
// within the wave (later program-order LDS store wins).
//
// Guard-free: INFV=1e30 absorbs adds; d^2 overflow -> inf sorts LARGE
// under unsigned-bitcast min (as do NaN / negative junk); junk cells
// (col<0 via INFV y-pad, col>=2048) only flow rightward, never into
// output col 2047. OOB ring writes land in pads. Seed DTW[-1][-1]=0
// enters as lane0/w0's initial uBp (diag of cell (0,0)).
//
// Output: row 2047 = w7/lane63 row 3, col 2047 = jB at tau0=2144
// (TAUMAX), s=14 (2144+29-126 = 2047).

#define NLEN   2048
#define NW     8
#define CSTEP  32
#define SPB    (CSTEP / 2)                           // 16 steps/block
#define DSKEW  160
#define PAD    128
#define RROW   (PAD + 2176)                          // cols -128..2175
#define YPAD   128
#define TAUMAX 2144
#define GTOT   (TAUMAX + (NW - 1) * DSKEW + CSTEP)   // 3296
#define INFV   1e30f

typedef float f32x2 __attribute__((ext_vector_type(2)));

__device__ __forceinline__ float dpp_shr1(float v, float inj) {
    int r = __builtin_amdgcn_update_dpp(
        __builtin_bit_cast(int, inj), __builtin_bit_cast(int, v),
        0x138 /*wave_shr:1*/, 0xF, 0xF, false /*lane0 keeps old=inj*/);
    return __builtin_bit_cast(float, r);
}
__device__ __forceinline__ float rdlane(float v, int l) {
    return __builtin_bit_cast(float,
        __builtin_amdgcn_readlane(__builtin_bit_cast(int, v), l));
}
// 3-input min on non-negative floats via unsigned bit-pattern compare;
// umin+umin fuses to a single v_min3_u32. NaN/inf/negative sort LARGE.
__device__ __forceinline__ float min3f(float a, float b, float c) {
    unsigned ia = __builtin_bit_cast(unsigned, a);
    unsigned ib = __builtin_bit_cast(unsigned, b);
    unsigned ic = __builtin_bit_cast(unsigned, c);
    unsigned m  = __builtin_elementwise_min(
                      __builtin_elementwise_min(ia, ib), ic);
    return __builtin_bit_cast(float, m);
}

__global__ __launch_bounds__(512, 1) void dtw_kernel(const float* __restrict__ X,
                                                     const float* __restrict__ Y,
                                                     float* __restrict__ out) {
    __shared__ __align__(16) float yB[YPAD + NLEN + YPAD];
    __shared__ float ring[(NW + 1) * RROW];
    float* yS = yB + YPAD;

    const int tid  = threadIdx.x;
    const int w    = tid >> 6;
    const int lane = tid & 63;

    {   // Y into the middle, INFV pads on both sides (junk col <-> junk y)
        const float4* Y4 = (const float4*)Y;
        float4* y4 = (float4*)(yB + YPAD);
        y4[tid] = Y4[tid];                           // 512 x float4 = 2048
        if (tid < YPAD) {
            yB[tid]               = INFV;
            yB[YPAD + NLEN + tid] = INFV;
        }
    }
    // Entire ring INFV: virtual row -1, pads, and unwritten tails.
    for (int k = tid; k < (NW + 1) * RROW; k += 512) ring[k] = INFV;
    __syncthreads();

    f32x2 xx0, xx1, xx2, xx3;
    {   // rows 4*tid..+3 = strip w rows 4*lane..+3
        const float4 xa = *(const float4*)&X[tid * 4];
        xx0 = (f32x2){xa.x, xa.x}; xx1 = (f32x2){xa.y, xa.y};
        xx2 = (f32x2){xa.z, xa.z}; xx3 = (f32x2){xa.w, xa.w};
    }

    // pBk: row-k col-B value of the previous step; a3p: row-3 col-A prev.
    float pB0 = INFV, pB1 = INFV, pB2 = INFV, pB3 = INFV;
    float a3p = INFV;
    float uBp = (tid == 0) ? 0.0f : INFV;   // DTW[-1][-1]=0 seed

    const float* ringR = ring + w * RROW + PAD;
    float*       ringW = ring + (w + 1) * RROW + PAD;

    for (int gb = 0; gb < GTOT; gb += CSTEP) {
        const int tau0 = gb - w * DSKEW;

        if (tau0 >= 0 && tau0 <= TAUMAX) {
            const float rblk = ringR[tau0 + lane];   // ring cols tau0..+63
            f32x2 y2[SPB];                           // y cols tau0-2l..+31
            {
                const f32x2* yp = (const f32x2*)(yS + (tau0 - 2 * lane));
                #pragma unroll
                for (int k = 0; k < SPB; ++k) y2[k] = yp[k];
            }
            float* wp = ringW + (tau0 - 2 * lane);
            const bool isout = (tau0 == TAUMAX) & (w == NW - 1) & (lane == 63);

            #pragma unroll
            for (int s = 0; s < SPB; ++s) {
                const float riA = rdlane(rblk, 2 * s);      // ring[tau0+2s]
                const float riB = rdlane(rblk, 2 * s + 1);  // ring[tau0+2s+1]
                const float uA  = dpp_shr1(a3p, riA);       // up for col A
                const float uB  = dpp_shr1(pB3, riB);       // up for col B
                const f32x2 yv = y2[s];
                f32x2 d0 = xx0 - yv;                        // v_pk_add_f32
                float n0A = fmaf(d0.x, d0.x, min3f(pB0, uA,  uBp));
                float n0B = fmaf(d0.y, d0.y, min3f(n0A, uB,  uA));
                f32x2 d1 = xx1 - yv;
                float n1A = fmaf(d1.x, d1.x, min3f(pB1, n0A, pB0));
                float n1B = fmaf(d1.y, d1.y, min3f(n1A, n0B, n0A));
                f32x2 d2 = xx2 - yv;
                float n2A = fmaf(d2.x, d2.x, min3f(pB2, n1A, pB1));
                float n2B = fmaf(d2.y, d2.y, min3f(n2A, n1B, n1A));
                f32x2 d3 = xx3 - yv;
                float n3A = fmaf(d3.x, d3.x, min3f(pB3, n2A, pB2));
                float n3B = fmaf(d3.y, d3.y, min3f(n3A, n2B, n2A));
                f32x2 wv; wv.x = n3A; wv.y = n3B;
                *(f32x2*)(wp + 2 * s) = wv;                 // ds_write_b64
                uBp = uB; a3p = n3A;
                pB0 = n0B; pB1 = n1B; pB2 = n2B; pB3 = n3B;
                if (s == 14 && isout) out[0] = sqrtf(n3B);  // col 2047
            }
        }
        __syncthreads();
    }
}

extern "C" void kernel_launch(void* const* d_in, const int* in_sizes, int n_in,
                              void* d_out, int out_size, void* d_ws, size_t ws_size,
                              hipStream_t stream) {
    const float* x = (const float*)d_in[0];
    const float* y = (const float*)d_in[1];
    (void)in_sizes; (void)n_in; (void)out_size; (void)d_ws; (void)ws_size;
    dtw_kernel<<<1, 512, 0, stream>>>(x, y, (float*)d_out);
}

// Round 10
// 180.580 us; speedup vs baseline: 1.4874x; 1.0970x over previous
//
#include <hip/hip_runtime.h>
#include <math.h>

// DTW 2048x2048, squared-diff cost, out = sqrt(DTW[2047][2047]).
//
// TWO-CU pipeline, FIXED handoff: 2 blocks x 4 waves (1 wave/SIMD on two
// CUs), 8 strips of 256 rows; strip g = 4*blockIdx + w; lane l owns strip
// rows 4l..4l+3. Engine = R7's proven C=2 core (cols jA=tau0+2s-2l, jB+1).
//
// WHY (rounds 0-9): lone-wave issue cadence ~4.8-5.3 cy/VALU is the wall
// (R0/R5/R7, dependency-structure-independent); 2 waves/SIMD convoy at
// only ~3.5-3.7 cy/op aggregate (R3/R9) and the ramp eats the gain ->
// single-CU ceiling = R7's 134.5us. R8 proved the 2-CU protocol CORRECT
// but throttled on per-step all-lane agent-atomic stores (WRITE_SIZE
// 570KB, ~450cy/step write-through). Fix: only lane63's boundary values
// are consumed and they're already in the LDS ring -> per block, ONE
// coalesced 256B LDS->global copy of newly-final cols [tau0-126,tau0-63],
// flag DEFERRED one block (fence placed BEFORE this block's copy, so
// vmcnt(0) waits only on ~4300cy-old stores = free).
// Model: 56 macro-blocks x 32 steps x ~133cy = 239Kcy = ~100us.
//
// Flag protocol (agent scope, cross-XCD safe -- R8-validated skeleton):
//   producer (b0,w3) end of block tau0:
//     if tau0>=128: __threadfence(); lane0 release-store flag = tau0-127
//     copy grow[tau0-126+lane] = ringLDS[tau0-126+lane]   (plain store)
//     if tau0==TAUMAX: __threadfence(); lane0 release-store flag = BIG
//   consumer (b1,w0) start of block tau0: needs cols <= min(tau0+63,2047)
//     final (cols >= 2048 are junk-safe: DP deps flow rightward only,
//     NaN/negative junk sorts LARGE under unsigned-bitcast min);
//     spins acquire on flag, then plain-loads grow (prefetched one block
//     ahead: spin target min(nt+63,2047), latency hidden under 32 steps).
//   No deadlock: b0 never waits; b1's targets are all eventually
//   published (final BIG). Flag memset to 0 per launch (capture-legal).
//
// Skews: strip g at skew g*192 (+EXTRA=64 for b1): b1w0 vs b0w3 diff =
// 256 >= 254 = steady-state requirement (126 lane-lag + 64 copy-gran +
// 64 deferred-flag). Intra-block LDS ring proof unchanged (DSKEW=192:
// producer completed tau0+128, lane63 wrote <= tau0+65 >= tau0+63).
// GTOT = 2112 + (7*192+64) + 64 = 3584.
//
// Per step (25 VALU): 2 rdlane + 2 dpp_shr1 (u conveyor) + 4 v_pk_add_f32
// + 8 min3 (unsigned-bitcast -> v_min3_u32) + 8 fma + 1 ds_write_b64.
// Guard-free INFV=1e30 scheme as R7 (pads absorb OOB; junk sorts large).
//
// Output: b1/w3 (strip 7), lane 63, row 3 = global 2047, col jB = 2047
// at tau0 = 2112 (TAUMAX), s = 30.

#define NLEN   2048
#define NWL    4
#define CSTEP  64
#define SPB    (CSTEP / 2)
#define DSKEW  192
#define EXTRA  64
#define PAD    128
#define RROW   (PAD + 2176)            // ring cols -128..2175 -> 2304 floats
#define YPAD   128
#define TAUMAX 2112
#define GTOT   (TAUMAX + 7 * DSKEW + EXTRA + CSTEP)   // 3584
#define FLAGBIG (1 << 20)
#define INFV   1e30f

typedef float f32x2 __attribute__((ext_vector_type(2)));

__device__ __forceinline__ float dpp_shr1(float v, float inj) {
    int r = __builtin_amdgcn_update_dpp(
        __builtin_bit_cast(int, inj), __builtin_bit_cast(int, v),
        0x138 /*wave_shr:1*/, 0xF, 0xF, false /*lane0 keeps old=inj*/);
    return __builtin_bit_cast(float, r);
}
__device__ __forceinline__ float rdlane(float v, int l) {
    return __builtin_bit_cast(float,
        __builtin_amdgcn_readlane(__builtin_bit_cast(int, v), l));
}
// 3-input min on non-negative floats via unsigned bit-pattern compare;
// umin+umin fuses to a single v_min3_u32. NaN/inf/negative sort LARGE.
__device__ __forceinline__ float min3f(float a, float b, float c) {
    unsigned ia = __builtin_bit_cast(unsigned, a);
    unsigned ib = __builtin_bit_cast(unsigned, b);
    unsigned ic = __builtin_bit_cast(unsigned, c);
    unsigned m  = __builtin_elementwise_min(
                      __builtin_elementwise_min(ia, ib), ic);
    return __builtin_bit_cast(float, m);
}
__device__ __forceinline__ void spinflag(int* flag, int target) {
    while (__hip_atomic_load(flag, __ATOMIC_ACQUIRE,
                             __HIP_MEMORY_SCOPE_AGENT) < target)
        __builtin_amdgcn_s_sleep(2);
}

// ---------------- 2-block (2-CU) kernel ----------------
__global__ __launch_bounds__(256, 1) void dtw_kernel(const float* __restrict__ X,
                                                     const float* __restrict__ Y,
                                                     float* __restrict__ out,
                                                     float* __restrict__ ws) {
    int*   flag = (int*)ws;
    float* grow = ws + 16 + PAD;       // global ring base (col 0)

    __shared__ __align__(16) float yB[YPAD + NLEN + YPAD];
    __shared__ float ring[(NWL + 1) * RROW];
    float* yS = yB + YPAD;

    const int tid  = threadIdx.x;
    const int w    = tid >> 6;
    const int lane = tid & 63;
    const int b    = blockIdx.x;
    const int skew = (4 * b + w) * DSKEW + (b ? EXTRA : 0);
    const bool isprod = (b == 0) & (w == 3);
    const bool iscons = (b == 1) & (w == 0);

    {   // Y into LDS middle, INFV pads on both sides
        const float4* Y4 = (const float4*)Y;
        float4* y4 = (float4*)(yB + YPAD);
        y4[tid]       = Y4[tid];
        y4[tid + 256] = Y4[tid + 256];
        if (tid < YPAD) {
            yB[tid]               = INFV;
            yB[YPAD + NLEN + tid] = INFV;
        }
    }
    for (int k = tid; k < (NWL + 1) * RROW; k += 256) ring[k] = INFV;
    __syncthreads();

    f32x2 xx0, xx1, xx2, xx3;
    {   // strip rows: 256*(4b+w) + 4*lane
        const float4 xa = *(const float4*)&X[b * 1024 + w * 256 + lane * 4];
        xx0 = (f32x2){xa.x, xa.x}; xx1 = (f32x2){xa.y, xa.y};
        xx2 = (f32x2){xa.z, xa.z}; xx3 = (f32x2){xa.w, xa.w};
    }

    float pB0 = INFV, pB1 = INFV, pB2 = INFV, pB3 = INFV;
    float a3p = INFV;
    float uBp = (b == 0 && tid == 0) ? 0.0f : INFV;  // DTW[-1][-1]=0 seed
    float gcur = INFV, gnext = INFV;                 // consumer prefetch regs

    const float* ringR = ring + w * RROW + PAD;
    float*       ringW = ring + (w + 1) * RROW + PAD;

    for (int gb = 0; gb < GTOT; gb += CSTEP) {
        const int tau0 = gb - skew;

        if (tau0 >= 0 && tau0 <= TAUMAX) {
            float rblk;
            if (iscons) {
                if (tau0 == 0) {                       // prologue: first block
                    spinflag(flag, 63);
                    gcur = grow[lane];
                }
                const int nt = tau0 + CSTEP;           // prefetch next block
                if (nt <= TAUMAX) {
                    int tgt = nt + 63;
                    if (tgt > NLEN - 1) tgt = NLEN - 1;
                    spinflag(flag, tgt);
                    gnext = grow[nt + lane];
                }
                rblk = gcur;
            } else {
                rblk = ringR[tau0 + lane];             // 1 coalesced ds_read
            }

            f32x2 y2[SPB];
            {
                const f32x2* yp = (const f32x2*)(yS + (tau0 - 2 * lane));
                #pragma unroll
                for (int k = 0; k < SPB; ++k) y2[k] = yp[k];
            }
            float* wp = ringW + (tau0 - 2 * lane);
            const bool isout = (b == 1) & (w == 3) & (lane == 63)
                             & (tau0 == TAUMAX);

            #pragma unroll
            for (int s = 0; s < SPB; ++s) {
                const float riA = rdlane(rblk, 2 * s);
                const float riB = rdlane(rblk, 2 * s + 1);
                const float uA  = dpp_shr1(a3p, riA);
                const float uB  = dpp_shr1(pB3, riB);
                const f32x2 yv = y2[s];
                f32x2 d0 = xx0 - yv;
                float n0A = fmaf(d0.x, d0.x, min3f(pB0, uA,  uBp));
                float n0B = fmaf(d0.y, d0.y, min3f(n0A, uB,  uA));
                f32x2 d1 = xx1 - yv;
                float n1A = fmaf(d1.x, d1.x, min3f(pB1, n0A, pB0));
                float n1B = fmaf(d1.y, d1.y, min3f(n1A, n0B, n0A));
                f32x2 d2 = xx2 - yv;
                float n2A = fmaf(d2.x, d2.x, min3f(pB2, n1A, pB1));
                float n2B = fmaf(d2.y, d2.y, min3f(n2A, n1B, n1A));
                f32x2 d3 = xx3 - yv;
                float n3A = fmaf(d3.x, d3.x, min3f(pB3, n2A, pB2));
                float n3B = fmaf(d3.y, d3.y, min3f(n3A, n2B, n2A));
                f32x2 wv; wv.x = n3A; wv.y = n3B;
                *(f32x2*)(wp + 2 * s) = wv;            // ds_write_b64
                uBp = uB; a3p = n3A;
                pB0 = n0B; pB1 = n1B; pB2 = n2B; pB3 = n3B;
                if (s == 30 && isout) out[0] = sqrtf(n3B);  // col 2047
            }

            if (isprod) {
                // deferred flag: covers copies issued at end of PREVIOUS
                // block (vmcnt long drained -> cheap fence)
                if (tau0 >= 128) {
                    __threadfence();
                    if (lane == 0)
                        __hip_atomic_store(flag, tau0 - 127, __ATOMIC_RELEASE,
                                           __HIP_MEMORY_SCOPE_AGENT);
                }
                // this block's newly-final cols: ONE coalesced 256B copy
                grow[tau0 - 126 + lane] = ringW[tau0 - 126 + lane];
                if (tau0 == TAUMAX) {                  // tail: publish all
                    __threadfence();
                    if (lane == 0)
                        __hip_atomic_store(flag, FLAGBIG, __ATOMIC_RELEASE,
                                           __HIP_MEMORY_SCOPE_AGENT);
                }
            }
            if (iscons) gcur = gnext;
        }
        __syncthreads();
    }
}

// ---------------- fallback: R7 single-block kernel (proven 134.5us) ----------------
#define FNW    4
#define FGTOT  (TAUMAX + (FNW - 1) * DSKEW + CSTEP)   // 2752

__global__ __launch_bounds__(256, 1) void dtw_kernel_fb(const float* __restrict__ X,
                                                        const float* __restrict__ Y,
                                                        float* __restrict__ out) {
    __shared__ __align__(16) float yB[YPAD + NLEN + YPAD];
    __shared__ float ring[(FNW + 1) * RROW];
    float* yS = yB + YPAD;

    const int tid  = threadIdx.x;
    const int w    = tid >> 6;
    const int lane = tid & 63;

    {
        const float4* Y4 = (const float4*)Y;
        float4* y4 = (float4*)(yB + YPAD);
        y4[tid]       = Y4[tid];
        y4[tid + 256] = Y4[tid + 256];
        if (tid < YPAD) {
            yB[tid]               = INFV;
            yB[YPAD + NLEN + tid] = INFV;
        }
    }
    for (int k = tid; k < (FNW + 1) * RROW; k += 256) ring[k] = INFV;
    __syncthreads();

    f32x2 xx0, xx1, xx2, xx3, xx4, xx5, xx6, xx7;
    {
        const float4 xa = *(const float4*)&X[tid * 8];
        const float4 xb = *(const float4*)&X[tid * 8 + 4];
        xx0 = (f32x2){xa.x, xa.x}; xx1 = (f32x2){xa.y, xa.y};
        xx2 = (f32x2){xa.z, xa.z}; xx3 = (f32x2){xa.w, xa.w};
        xx4 = (f32x2){xb.x, xb.x}; xx5 = (f32x2){xb.y, xb.y};
        xx6 = (f32x2){xb.z, xb.z}; xx7 = (f32x2){xb.w, xb.w};
    }

    float pB0 = INFV, pB1 = INFV, pB2 = INFV, pB3 = INFV;
    float pB4 = INFV, pB5 = INFV, pB6 = INFV, pB7 = INFV;
    float a7p = INFV;
    float uBp = (tid == 0) ? 0.0f : INFV;

    const float* ringR = ring + w * RROW + PAD;
    float*       ringW = ring + (w + 1) * RROW + PAD;

    for (int gb = 0; gb < FGTOT; gb += CSTEP) {
        const int tau0 = gb - w * DSKEW;

        if (tau0 >= 0 && tau0 <= TAUMAX) {
            const float rblk = ringR[tau0 + lane];
            f32x2 y2[SPB];
            {
                const f32x2* yp = (const f32x2*)(yS + (tau0 - 2 * lane));
                #pragma unroll
                for (int k = 0; k < SPB; ++k) y2[k] = yp[k];
            }
            float* wp = ringW + (tau0 - 2 * lane);
            const bool isout = (tau0 == TAUMAX) & (w == FNW - 1) & (lane == 63);

            #pragma unroll
            for (int s = 0; s < SPB; ++s) {
                const float riA = rdlane(rblk, 2 * s);
                const float riB = rdlane(rblk, 2 * s + 1);
                const float uA  = dpp_shr1(a7p, riA);
                const float uB  = dpp_shr1(pB7, riB);
                const f32x2 yv = y2[s];
                f32x2 d0 = xx0 - yv;
                float n0A = fmaf(d0.x, d0.x, min3f(pB0, uA,  uBp));
                float n0B = fmaf(d0.y, d0.y, min3f(n0A, uB,  uA));
                f32x2 d1 = xx1 - yv;
                float n1A = fmaf(d1.x, d1.x, min3f(pB1, n0A, pB0));
                float n1B = fmaf(d1.y, d1.y, min3f(n1A, n0B, n0A));
                f32x2 d2 = xx2 - yv;
                float n2A = fmaf(d2.x, d2.x, min3f(pB2, n1A, pB1));
                float n2B = fmaf(d2.y, d2.y, min3f(n2A, n1B, n1A));
                f32x2 d3 = xx3 - yv;
                float n3A = fmaf(d3.x, d3.x, min3f(pB3, n2A, pB2));
                float n3B = fmaf(d3.y, d3.y, min3f(n3A, n2B, n2A));
                f32x2 d4 = xx4 - yv;
                float n4A = fmaf(d4.x, d4.x, min3f(pB4, n3A, pB3));
                float n4B = fmaf(d4.y, d4.y, min3f(n4A, n3B, n3A));
                f32x2 d5 = xx5 - yv;
                float n5A = fmaf(d5.x, d5.x, min3f(pB5, n4A, pB4));
                float n5B = fmaf(d5.y, d5.y, min3f(n5A, n4B, n4A));
                f32x2 d6 = xx6 - yv;
                float n6A = fmaf(d6.x, d6.x, min3f(pB6, n5A, pB5));
                float n6B = fmaf(d6.y, d6.y, min3f(n6A, n5B, n5A));
                f32x2 d7 = xx7 - yv;
                float n7A = fmaf(d7.x, d7.x, min3f(pB7, n6A, pB6));
                float n7B = fmaf(d7.y, d7.y, min3f(n7A, n6B, n6A));
                f32x2 wv; wv.x = n7A; wv.y = n7B;
                *(f32x2*)(wp + 2 * s) = wv;
                uBp = uB; a7p = n7A;
                pB0 = n0B; pB1 = n1B; pB2 = n2B; pB3 = n3B;
                pB4 = n4B; pB5 = n5B; pB6 = n6B; pB7 = n7B;
                if (s == 30 && isout) out[0] = sqrtf(n7B);
            }
        }
        __syncthreads();
    }
}

extern "C" void kernel_launch(void* const* d_in, const int* in_sizes, int n_in,
                              void* d_out, int out_size, void* d_ws, size_t ws_size,
                              hipStream_t stream) {
    const float* x = (const float*)d_in[0];
    const float* y = (const float*)d_in[1];
    (void)in_sizes; (void)n_in; (void)out_size;
    if (d_ws != nullptr && ws_size >= 16384) {
        hipMemsetAsync(d_ws, 0, 4, stream);          // zero the flag
        dtw_kernel<<<2, 256, 0, stream>>>(x, y, (float*)d_out, (float*)d_ws);
    } else {
        dtw_kernel_fb<<<1, 256, 0, stream>>>(x, y, (float*)d_out);
    }
}